// Round 14
// baseline (224.500 us; speedup 1.0000x reference)
//
#include <hip/hip_runtime.h>
#include <hip/hip_bf16.h>

#define N_NODES 50000
#define N_EDGES 800000
#define IN_F    512
#define HEADS   8
#define DHEAD   32
#define NHD     256            // HEADS*DHEAD
#define SLOPE   0.2f
#define EPS_F   1e-16f
#define N_SBLK  ((N_NODES + 255) / 256)   // 196 scan blocks
#define NB_M    ((N_NODES + 127) / 128)   // 391 M-tiles
#define NB_GEMM (NB_M * 2)                // 782 gemm blocks (2 N-tiles of 128)
#define NB_HIST ((N_EDGES + 4095) / 4096) // 196 hist blocks
#define NB_FILL ((N_EDGES + 255) / 256)   // 3125 fill blocks
#define NB_XCST ((N_NODES * IN_F / 8 + 255) / 256)  // 12500 x-cast blocks

typedef __attribute__((ext_vector_type(8))) short short8;
typedef __attribute__((ext_vector_type(4))) float f32x4;
typedef __attribute__((ext_vector_type(4))) unsigned short u16x4;
typedef __attribute__((ext_vector_type(4))) unsigned int u32x4;

__device__ __forceinline__ unsigned short f2bf(float f) {
  unsigned int u = __float_as_uint(f);
  unsigned int r = u + 0x7FFFu + ((u >> 16) & 1u);   // round-to-nearest-even
  return (unsigned short)(r >> 16);
}
__device__ __forceinline__ float bf2f(unsigned short s) {
  return __uint_as_float(((unsigned int)s) << 16);
}
// packed f32x2 -> bf16x2 (v_cvt_pk_bf16_f32, RNE)
__device__ __forceinline__ unsigned int pkbf(float a, float b) {
  __hip_bfloat162 t = __float22bfloat162_rn(float2{a, b});
  unsigned int r;
  __builtin_memcpy(&r, &t, sizeof(r));
  return r;
}
__device__ __forceinline__ void gload_lds16(const void* g, void* l) {
  __builtin_amdgcn_global_load_lds((const __attribute__((address_space(1))) void*)g,
                                   (__attribute__((address_space(3))) void*)l, 16, 0, 0);
}

// ---- prep: blocks [0, NB_XCST)           : cast x -> xb (bf16, in d_out)
//            blocks [NB_XCST, NB_XCST+512) : cast W -> WbT [c][k] bf16
//            blocks [NB_XCST+512, +NB_HIST): degree histogram (deg pre-zeroed)
__global__ __launch_bounds__(256) void k_prep(const float* __restrict__ x,
                                              unsigned short* __restrict__ xb,
                                              const float* __restrict__ W,
                                              unsigned short* __restrict__ WbT,
                                              const int* __restrict__ ei,
                                              int* __restrict__ deg) {
  int b = blockIdx.x;
  if (b < NB_XCST) {
    size_t id = (size_t)b * 256 + threadIdx.x;     // 3.2M threads, 8 elems each
    const float4* src = (const float4*)(x + id * 8);
    float4 lo = src[0], hi = src[1];
    u32x4 v = { pkbf(lo.x, lo.y), pkbf(lo.z, lo.w),
                pkbf(hi.x, hi.y), pkbf(hi.z, hi.w) };
    *(u32x4*)(xb + id * 8) = v;
  } else if (b < NB_XCST + 512) {
    int id = (b - NB_XCST) * 256 + threadIdx.x;    // 0..131071
    if (id < NHD * IN_F) {
      int c = id >> 9, k = id & 511;
      WbT[id] = f2bf(W[(c >> 5) * (IN_F * DHEAD) + k * DHEAD + (c & 31)]);
    }
  } else {
    int hb_ = b - NB_XCST - 512;
    int end = min(hb_ * 4096 + 4096, N_EDGES);
    for (int e = hb_ * 4096 + threadIdx.x; e < end; e += 256)
      atomicAdd(&deg[ei[e]], 1);
  }
}

// ---- MFMA GEMM (m97 clone; blocks 0..781) + CSR fill (blocks 782..3906).
// GEMM: tile 128(M)x128(N), BK=64, 4 waves 2x2 (wave = 64x64, 4x4 acc).
// BOTH A and B staged via global_load_lds width=16 (no VGPR roundtrip,
// no in-loop casts) into LINEAR LDS [row][64] bf16 (2-phase regime).
// Fill runs in tail blocks: hides its ~18us inside the GEMM's shadow.
// Epilogue fuses s_src/s_dst score dots from f32 accumulators.
__global__ __launch_bounds__(256) void k_gemm_mfma(const unsigned short* __restrict__ xb,
                                                   const unsigned short* __restrict__ WbT,
                                                   unsigned short* __restrict__ hb,
                                                   const float* __restrict__ a,
                                                   float* __restrict__ s_src,
                                                   float* __restrict__ s_dst,
                                                   const int* __restrict__ ei,
                                                   int* __restrict__ cursor,
                                                   int* __restrict__ edst) {
  if (blockIdx.x >= NB_GEMM) {            // ---- CSR-fill path (overlapped)
    int e = (blockIdx.x - NB_GEMM) * 256 + threadIdx.x;
    if (e < N_EDGES) {
      int p = atomicAdd(&cursor[ei[e]], 1);
      edst[p] = ei[N_EDGES + e];
    }
    return;
  }

  __shared__ unsigned short As[128 * 64];   // 16 KB
  __shared__ unsigned short Bs[128 * 64];   // 16 KB
  const int tid  = threadIdx.x;
  const int lane = tid & 63;
  const int wid  = tid >> 6;
  const int wr   = wid >> 1;                // 0..1 row half (64 rows)
  const int wc   = wid & 1;                 // 0..1 col half (64 cols)
  const int bm   = (blockIdx.x >> 1) * 128;
  const int bn   = (blockIdx.x & 1) * 128;

  // staging: wave wid covers A rows 32*wid..+31 and B rows (cols) 32*wid..+31,
  // 4 gload_lds iters each (8 rows x 8 quads per iter, lane = r*8+q)
  const int rl0 = 32 * wid + (lane >> 3);          // iter-0 local row
  const int qq  = lane & 7;                        // 16B quad index
  const unsigned short* gA = xb + (size_t)min(bm + rl0, N_NODES - 1) * IN_F + qq * 8;
  const unsigned short* gB = WbT + (size_t)(bn + rl0) * IN_F + qq * 8;
  unsigned short* lA = &As[(size_t)(32 * wid) * 64 + lane * 8];
  unsigned short* lB = &Bs[(size_t)(32 * wid) * 64 + lane * 8];

  f32x4 acc[4][4] = {};
  const int dl = lane & 15;
  const int qg = lane >> 4;

#pragma unroll
  for (int t = 0; t < 8; ++t) {
    const int k0 = t * 64;
    __syncthreads();                       // prev-step LDS reads done
#pragma unroll
    for (int it = 0; it < 4; ++it) {       // A,B: 4 x gload_lds each (8 rows)
      gload_lds16(gA + k0 + (size_t)it * 8 * IN_F, lA + it * 8 * 64);
      gload_lds16(gB + k0 + (size_t)it * 8 * IN_F, lB + it * 8 * 64);
    }
    __syncthreads();                       // staging visible

#pragma unroll
    for (int kk = 0; kk < 2; ++kk) {
      short8 af[4], bfr[4];
#pragma unroll
      for (int i = 0; i < 4; ++i)
        af[i] = *(const short8*)&As[(wr * 64 + i * 16 + dl) * 64 + kk * 32 + qg * 8];
#pragma unroll
      for (int j = 0; j < 4; ++j)
        bfr[j] = *(const short8*)&Bs[(wc * 64 + j * 16 + dl) * 64 + kk * 32 + qg * 8];
#pragma unroll
      for (int i = 0; i < 4; ++i)
#pragma unroll
        for (int j = 0; j < 4; ++j)
          acc[i][j] = __builtin_amdgcn_mfma_f32_16x16x32_bf16(af[i], bfr[j], acc[i][j], 0, 0, 0);
    }
  }

  // ---- epilogue: hb (bf16) write + fused scores from f32 acc
  // C/D layout: col = cb + j*16 + dl, row = bm + wr*64 + i*16 + qg*4 + q
  const int cb = bn + wc * 64;              // 64-col span -> heads h0, h0+1
  const int h0 = cb >> 5, h1 = h0 + 1;
  const float as00 = a[h0 * 64 + dl],      as01 = a[h0 * 64 + 16 + dl];
  const float as10 = a[h1 * 64 + dl],      as11 = a[h1 * 64 + 16 + dl];
  const float ad00 = a[h0 * 64 + 32 + dl], ad01 = a[h0 * 64 + 48 + dl];
  const float ad10 = a[h1 * 64 + 32 + dl], ad11 = a[h1 * 64 + 48 + dl];

#pragma unroll
  for (int i = 0; i < 4; ++i) {
#pragma unroll
    for (int q = 0; q < 4; ++q) {
      int row = bm + wr * 64 + i * 16 + qg * 4 + q;
      float ss0 = acc[i][0][q] * as00 + acc[i][1][q] * as01;
      float ss1 = acc[i][2][q] * as10 + acc[i][3][q] * as11;
      float sd0 = acc[i][0][q] * ad00 + acc[i][1][q] * ad01;
      float sd1 = acc[i][2][q] * ad10 + acc[i][3][q] * ad11;
#pragma unroll
      for (int o = 1; o < 16; o <<= 1) {
        ss0 += __shfl_xor(ss0, o);
        ss1 += __shfl_xor(ss1, o);
        sd0 += __shfl_xor(sd0, o);
        sd1 += __shfl_xor(sd1, o);
      }
      if (row < N_NODES) {
#pragma unroll
        for (int j = 0; j < 4; ++j)
          hb[(size_t)row * NHD + cb + j * 16 + dl] = f2bf(acc[i][j][q]);
        if (dl == 0) {
          s_src[row * 8 + h0] = ss0;
          s_src[row * 8 + h1] = ss1;
          s_dst[row * 8 + h0] = sd0;
          s_dst[row * 8 + h1] = sd1;
        }
      }
    }
  }
}

// ---- CSR build: per-block degree sums (196 blocks x 256)
__global__ __launch_bounds__(256) void k_bsum(const int* __restrict__ deg,
                                              int* __restrict__ bsum) {
  __shared__ int sm[4];
  int i = blockIdx.x * 256 + threadIdx.x;
  int v = (i < N_NODES) ? deg[i] : 0;
#pragma unroll
  for (int o = 1; o < 64; o <<= 1) v += __shfl_xor(v, o);
  if ((threadIdx.x & 63) == 0) sm[threadIdx.x >> 6] = v;
  __syncthreads();
  if (threadIdx.x == 0) bsum[blockIdx.x] = sm[0] + sm[1] + sm[2] + sm[3];
}

// full scan: each block re-scans the 196 block sums, then its 256 degrees
__global__ __launch_bounds__(256) void k_scan_main(const int* __restrict__ deg,
                                                   const int* __restrict__ bsum,
                                                   int* __restrict__ rowptr,
                                                   int* __restrict__ cursor) {
  __shared__ int sb[256];
  __shared__ int sm[256];
  const int t = threadIdx.x;
  const int b = blockIdx.x;
  int bv = (t < N_SBLK) ? bsum[t] : 0;
  sb[t] = bv;
  int i = b * 256 + t;
  int v = (i < N_NODES) ? deg[i] : 0;
  sm[t] = v;
  __syncthreads();
#pragma unroll
  for (int o = 1; o < 256; o <<= 1) {
    int u1 = (t >= o) ? sb[t - o] : 0;
    int u2 = (t >= o) ? sm[t - o] : 0;
    __syncthreads();
    sb[t] += u1;
    sm[t] += u2;
    __syncthreads();
  }
  int boff = (b > 0) ? sb[b - 1] : 0;
  if (i < N_NODES) {
    int ex = boff + sm[t] - v;
    rowptr[i] = ex;
    cursor[i] = ex;
  }
  if (b == 0 && t == 0) rowptr[N_NODES] = sb[255];
}

// ---- fused aggregation: one wave per node, m=0 softmax, 2-way unrolled.
// At the random-gather roofline (~6 TB/s logical, R3 vs R13 cross-check).
__global__ __launch_bounds__(256) void k_aggr(const int* __restrict__ rowptr,
                                              const int* __restrict__ edst,
                                              const float* __restrict__ s_src,
                                              const float* __restrict__ s_dst,
                                              const unsigned short* __restrict__ hb,
                                              float* __restrict__ out) {
  int n = (int)((blockIdx.x * blockDim.x + threadIdx.x) >> 6);
  if (n >= N_NODES) return;
  n = __builtin_amdgcn_readfirstlane(n);
  const int lane = threadIdx.x & 63;
  const int head = lane >> 3;
  const float ssrc = s_src[n * 8 + head];
  int i = rowptr[n];
  const int iend = rowptr[n + 1];
  float den = 0.f;
  f32x4 acc = {0.f, 0.f, 0.f, 0.f};
  for (; i + 1 < iend; i += 2) {
    int d0 = edst[i], d1 = edst[i + 1];
    float v0 = ssrc + s_dst[d0 * 8 + head];
    float v1 = ssrc + s_dst[d1 * 8 + head];
    u16x4 h0 = *(const u16x4*)(hb + (size_t)d0 * NHD + lane * 4);
    u16x4 h1 = *(const u16x4*)(hb + (size_t)d1 * NHD + lane * 4);
    v0 = v0 >= 0.f ? v0 : SLOPE * v0;
    v1 = v1 >= 0.f ? v1 : SLOPE * v1;
    float e0 = __expf(v0), e1 = __expf(v1);
    den += e0 + e1;
    acc.x += e0 * bf2f(h0.x) + e1 * bf2f(h1.x);
    acc.y += e0 * bf2f(h0.y) + e1 * bf2f(h1.y);
    acc.z += e0 * bf2f(h0.z) + e1 * bf2f(h1.z);
    acc.w += e0 * bf2f(h0.w) + e1 * bf2f(h1.w);
  }
  if (i < iend) {
    int d0 = edst[i];
    float v0 = ssrc + s_dst[d0 * 8 + head];
    v0 = v0 >= 0.f ? v0 : SLOPE * v0;
    float e0 = __expf(v0);
    u16x4 h0 = *(const u16x4*)(hb + (size_t)d0 * NHD + lane * 4);
    den += e0;
    acc.x += e0 * bf2f(h0.x);
    acc.y += e0 * bf2f(h0.y);
    acc.z += e0 * bf2f(h0.z);
    acc.w += e0 * bf2f(h0.w);
  }
  float inv = 1.f / (den + EPS_F);         // deg==0: acc=0 -> out=0
  *(f32x4*)(out + (size_t)n * NHD + lane * 4) = acc * inv;
}

extern "C" void kernel_launch(void* const* d_in, const int* in_sizes, int n_in,
                              void* d_out, int out_size, void* d_ws, size_t ws_size,
                              hipStream_t stream) {
  const float* x  = (const float*)d_in[0];
  const int*   ei = (const int*)d_in[1];
  const float* W  = (const float*)d_in[2];
  const float* a  = (const float*)d_in[3];
  float* out = (float*)d_out;
  // xb (x cast to bf16) lives in d_out: 50000*512 bf16 == 50000*256 f32 exactly.
  // It is consumed by the GEMM, then d_out is overwritten by k_aggr at the end.
  unsigned short* xb = (unsigned short*)d_out;

  // workspace layout (~33 MB, 16B-aligned blocks)
  unsigned short* hb  = (unsigned short*)d_ws;                 // 12,800,000 u16
  unsigned short* WbT = hb + (size_t)N_NODES * NHD;            // 131,072 u16
  float* s_src = (float*)(WbT + (size_t)NHD * IN_F);           // 400,000 f
  float* s_dst = s_src + (size_t)N_NODES * HEADS;              // 400,000 f
  int* deg    = (int*)(s_dst + (size_t)N_NODES * HEADS);       // 50,000
  int* cursor = deg + N_NODES;                                 // 50,000
  int* rowptr = cursor + N_NODES;                              // 50,001 (pad 50,008)
  int* bsum   = rowptr + 50008;                                // 196 (pad 256)
  int* edst   = bsum + 256;                                    // 800,000

  hipMemsetAsync(deg, 0, (size_t)N_NODES * sizeof(int), stream);
  k_prep<<<NB_XCST + 512 + NB_HIST, 256, 0, stream>>>(x, xb, W, WbT, ei, deg);
  k_bsum<<<N_SBLK, 256, 0, stream>>>(deg, bsum);
  k_scan_main<<<N_SBLK, 256, 0, stream>>>(deg, bsum, rowptr, cursor);
  k_gemm_mfma<<<NB_GEMM + NB_FILL, 256, 0, stream>>>(xb, WbT, hb, a, s_src, s_dst, ei, cursor, edst);
  k_aggr<<<(N_NODES * 64 + 255) / 256, 256, 0, stream>>>(rowptr, edst, s_src, s_dst, hb, out);
}

// Round 15
// 173.817 us; speedup vs baseline: 1.2916x; 1.2916x over previous
//
#include <hip/hip_runtime.h>

#define N_NODES 50000
#define N_EDGES 800000
#define IN_F    512
#define HEADS   8
#define DHEAD   32
#define NHD     256            // HEADS*DHEAD
#define SLOPE   0.2f
#define EPS_F   1e-16f
#define N_SBLK  ((N_NODES + 255) / 256)   // 196 scan blocks
#define NB_GEMM ((N_NODES + 127) / 128)   // 391 gemm blocks (BM=128)
#define NB_HIST ((N_EDGES + 4095) / 4096) // 196 hist blocks (4096 edges each)

typedef __attribute__((ext_vector_type(8))) short short8;
typedef __attribute__((ext_vector_type(4))) float f32x4;
typedef __attribute__((ext_vector_type(4))) unsigned short u16x4;

__device__ __forceinline__ unsigned short f2bf(float f) {
  unsigned int u = __float_as_uint(f);
  unsigned int r = u + 0x7FFFu + ((u >> 16) & 1u);   // round-to-nearest-even
  return (unsigned short)(r >> 16);
}
__device__ __forceinline__ float bf2f(unsigned short s) {
  return __uint_as_float(((unsigned int)s) << 16);
}
__device__ __forceinline__ void gload_lds16(const void* g, void* l) {
  __builtin_amdgcn_global_load_lds((const __attribute__((address_space(1))) void*)g,
                                   (__attribute__((address_space(3))) void*)l, 16, 0, 0);
}

// ---- cast W[h][k][d] (f32) -> WbT[c][k] (bf16), c = h*32+d; also zero deg
__global__ void k_cast_w(const float* __restrict__ W, unsigned short* __restrict__ WbT,
                         int* __restrict__ deg) {
  int id = blockIdx.x * blockDim.x + threadIdx.x;
  if (id < NHD * IN_F) {
    int c = id >> 9, k = id & 511;
    WbT[id] = f2bf(W[(c >> 5) * (IN_F * DHEAD) + k * DHEAD + (c & 31)]);
  }
  if (id < N_NODES) deg[id] = 0;
}

// ---- MFMA GEMM (blocks 0..390, 512 thr) + edge histogram (blocks 391..586).
// R7 structure scaled to 8 waves: tile 128(M)x256(N), BK=64, each wave 64x64.
// LDS 48 KB (3 blocks/CU = 24 waves/CU vs R7's 16 -> more TLP to hide the
// stage-drain). Same conflict-free XOR quad swizzle (slot p = q ^ (row&7)),
// same global_load_lds B staging (4/thread), A staged once per 128 rows.
// Epilogue fuses s_src/s_dst score dots from f32 accumulators.
__global__ __launch_bounds__(512) void k_gemm_mfma(const float* __restrict__ x,
                                                   const unsigned short* __restrict__ WbT,
                                                   unsigned short* __restrict__ hb,
                                                   const float* __restrict__ a,
                                                   float* __restrict__ s_src,
                                                   float* __restrict__ s_dst,
                                                   const int* __restrict__ ei,
                                                   int* __restrict__ deg) {
  if (blockIdx.x >= NB_GEMM) {            // ---- histogram path (overlapped)
    int b = blockIdx.x - NB_GEMM;
    int end = min(b * 4096 + 4096, N_EDGES);
    for (int e = b * 4096 + threadIdx.x; e < end; e += 512)
      atomicAdd(&deg[ei[e]], 1);
    return;
  }

  __shared__ unsigned short As[128 * 64];   // 16 KB
  __shared__ unsigned short Bs[256 * 64];   // 32 KB
  const int tid  = threadIdx.x;
  const int lane = tid & 63;
  const int wid  = tid >> 6;                // 0..7
  const int wr   = wid >> 2;                // 0..1: row half (64 rows)
  const int wc   = wid & 3;                 // 0..3: col quarter (64 cols)
  const int bm   = blockIdx.x * 128;

  // A staging (reg + cast): slots tid and tid+512 (128 rows x 8 quads)
  const int ar0 = tid >> 3,          ap0 = tid & 7,          aq0 = ap0 ^ (ar0 & 7);
  const int ar1 = (tid + 512) >> 3,  ap1 = tid & 7,          aq1 = ap1 ^ (ar1 & 7);
  const float* gA0 = x + (size_t)min(bm + ar0, N_NODES - 1) * IN_F + aq0 * 8;
  const float* gA1 = x + (size_t)min(bm + ar1, N_NODES - 1) * IN_F + aq1 * 8;
  unsigned short* lA0 = &As[(ar0 * 8 + ap0) * 8];
  unsigned short* lA1 = &As[(ar1 * 8 + ap1) * 8];

  // B staging (async gload_lds): wave wid stages slots 256*wid + 64*it + lane
  const int bs = 256 * wid + lane;
  const int brow = bs >> 3, bp = bs & 7, bq = bp ^ (brow & 7);
  const unsigned short* gB = WbT + (size_t)brow * IN_F + bq * 8;
  unsigned short* lB = &Bs[(size_t)bs * 8];

  f32x4 acc[4][4] = {};
  const int dl = lane & 15;
  const int qg = lane >> 4;

#pragma unroll
  for (int t = 0; t < 8; ++t) {
    const int k0 = t * 64;
    __syncthreads();                      // prev-step LDS reads done
#pragma unroll
    for (int it = 0; it < 4; ++it)        // B: 4 x gload_lds (8 rows each)
      gload_lds16(gB + k0 + (size_t)it * 8 * IN_F, lB + it * 64 * 8);
    {                                     // A: 2 slots, f32 -> bf16 in-reg
      float4 a00 = *(const float4*)(gA0 + k0);
      float4 a01 = *(const float4*)(gA0 + k0 + 4);
      float4 a10 = *(const float4*)(gA1 + k0);
      float4 a11 = *(const float4*)(gA1 + k0 + 4);
      short8 v0, v1;
      v0[0] = (short)f2bf(a00.x); v0[1] = (short)f2bf(a00.y);
      v0[2] = (short)f2bf(a00.z); v0[3] = (short)f2bf(a00.w);
      v0[4] = (short)f2bf(a01.x); v0[5] = (short)f2bf(a01.y);
      v0[6] = (short)f2bf(a01.z); v0[7] = (short)f2bf(a01.w);
      v1[0] = (short)f2bf(a10.x); v1[1] = (short)f2bf(a10.y);
      v1[2] = (short)f2bf(a10.z); v1[3] = (short)f2bf(a10.w);
      v1[4] = (short)f2bf(a11.x); v1[5] = (short)f2bf(a11.y);
      v1[6] = (short)f2bf(a11.z); v1[7] = (short)f2bf(a11.w);
      *(short8*)lA0 = v0;
      *(short8*)lA1 = v1;
    }
    __syncthreads();                      // staging visible

#pragma unroll
    for (int kk = 0; kk < 2; ++kk) {
      const int kq = kk * 4 + qg;
      short8 af[4], bfr[4];
#pragma unroll
      for (int i = 0; i < 4; ++i) {
        int r = wr * 64 + i * 16 + dl;
        af[i] = *(const short8*)&As[(r * 8 + (kq ^ (r & 7))) * 8];
      }
#pragma unroll
      for (int j = 0; j < 4; ++j) {
        int c = wc * 64 + j * 16 + dl;
        bfr[j] = *(const short8*)&Bs[(c * 8 + (kq ^ (c & 7))) * 8];
      }
#pragma unroll
      for (int i = 0; i < 4; ++i)
#pragma unroll
        for (int j = 0; j < 4; ++j)
          acc[i][j] = __builtin_amdgcn_mfma_f32_16x16x32_bf16(af[i], bfr[j], acc[i][j], 0, 0, 0);
    }
  }

  // ---- epilogue: hb (bf16) write + fused scores from f32 acc
  // C/D layout: col = wc*64 + j*16 + dl, row = bm + wr*64 + i*16 + qg*4 + q
  const int h0 = 2 * wc, h1 = 2 * wc + 1;
  const int cb = wc * 64;
  const float as00 = a[h0 * 64 + dl],      as01 = a[h0 * 64 + 16 + dl];
  const float as10 = a[h1 * 64 + dl],      as11 = a[h1 * 64 + 16 + dl];
  const float ad00 = a[h0 * 64 + 32 + dl], ad01 = a[h0 * 64 + 48 + dl];
  const float ad10 = a[h1 * 64 + 32 + dl], ad11 = a[h1 * 64 + 48 + dl];

#pragma unroll
  for (int i = 0; i < 4; ++i) {
#pragma unroll
    for (int q = 0; q < 4; ++q) {
      int row = bm + wr * 64 + i * 16 + qg * 4 + q;
      float ss0 = acc[i][0][q] * as00 + acc[i][1][q] * as01;
      float ss1 = acc[i][2][q] * as10 + acc[i][3][q] * as11;
      float sd0 = acc[i][0][q] * ad00 + acc[i][1][q] * ad01;
      float sd1 = acc[i][2][q] * ad10 + acc[i][3][q] * ad11;
#pragma unroll
      for (int o = 1; o < 16; o <<= 1) {
        ss0 += __shfl_xor(ss0, o);
        ss1 += __shfl_xor(ss1, o);
        sd0 += __shfl_xor(sd0, o);
        sd1 += __shfl_xor(sd1, o);
      }
      if (row < N_NODES) {
#pragma unroll
        for (int j = 0; j < 4; ++j)
          hb[(size_t)row * NHD + cb + j * 16 + dl] = f2bf(acc[i][j][q]);
        if (dl == 0) {
          s_src[row * 8 + h0] = ss0;
          s_src[row * 8 + h1] = ss1;
          s_dst[row * 8 + h0] = sd0;
          s_dst[row * 8 + h1] = sd1;
        }
      }
    }
  }
}

// ---- CSR build: per-block degree sums (196 blocks x 256)
__global__ __launch_bounds__(256) void k_bsum(const int* __restrict__ deg,
                                              int* __restrict__ bsum) {
  __shared__ int sm[4];
  int i = blockIdx.x * 256 + threadIdx.x;
  int v = (i < N_NODES) ? deg[i] : 0;
#pragma unroll
  for (int o = 1; o < 64; o <<= 1) v += __shfl_xor(v, o);
  if ((threadIdx.x & 63) == 0) sm[threadIdx.x >> 6] = v;
  __syncthreads();
  if (threadIdx.x == 0) bsum[blockIdx.x] = sm[0] + sm[1] + sm[2] + sm[3];
}

// full scan: each block re-scans the 196 block sums, then its 256 degrees
__global__ __launch_bounds__(256) void k_scan_main(const int* __restrict__ deg,
                                                   const int* __restrict__ bsum,
                                                   int* __restrict__ rowptr,
                                                   int* __restrict__ cursor) {
  __shared__ int sb[256];
  __shared__ int sm[256];
  const int t = threadIdx.x;
  const int b = blockIdx.x;
  int bv = (t < N_SBLK) ? bsum[t] : 0;
  sb[t] = bv;
  int i = b * 256 + t;
  int v = (i < N_NODES) ? deg[i] : 0;
  sm[t] = v;
  __syncthreads();
#pragma unroll
  for (int o = 1; o < 256; o <<= 1) {
    int u1 = (t >= o) ? sb[t - o] : 0;
    int u2 = (t >= o) ? sm[t - o] : 0;
    __syncthreads();
    sb[t] += u1;
    sm[t] += u2;
    __syncthreads();
  }
  int boff = (b > 0) ? sb[b - 1] : 0;
  if (i < N_NODES) {
    int ex = boff + sm[t] - v;
    rowptr[i] = ex;
    cursor[i] = ex;
  }
  if (b == 0 && t == 0) rowptr[N_NODES] = sb[255];
}

__global__ void k_fill(const int* __restrict__ ei, int* __restrict__ cursor,
                       int* __restrict__ edst) {
  int e = blockIdx.x * blockDim.x + threadIdx.x;
  if (e >= N_EDGES) return;
  int p = atomicAdd(&cursor[ei[e]], 1);
  edst[p] = ei[N_EDGES + e];
}

// ---- fused aggregation: one wave per node, m=0 softmax, 2-way unrolled.
// At the random-gather roofline (~6 TB/s logical, R3 vs R13 cross-check).
__global__ __launch_bounds__(256) void k_aggr(const int* __restrict__ rowptr,
                                              const int* __restrict__ edst,
                                              const float* __restrict__ s_src,
                                              const float* __restrict__ s_dst,
                                              const unsigned short* __restrict__ hb,
                                              float* __restrict__ out) {
  int n = (int)((blockIdx.x * blockDim.x + threadIdx.x) >> 6);
  if (n >= N_NODES) return;
  n = __builtin_amdgcn_readfirstlane(n);
  const int lane = threadIdx.x & 63;
  const int head = lane >> 3;
  const float ssrc = s_src[n * 8 + head];
  int i = rowptr[n];
  const int iend = rowptr[n + 1];
  float den = 0.f;
  f32x4 acc = {0.f, 0.f, 0.f, 0.f};
  for (; i + 1 < iend; i += 2) {
    int d0 = edst[i], d1 = edst[i + 1];
    float v0 = ssrc + s_dst[d0 * 8 + head];
    float v1 = ssrc + s_dst[d1 * 8 + head];
    u16x4 h0 = *(const u16x4*)(hb + (size_t)d0 * NHD + lane * 4);
    u16x4 h1 = *(const u16x4*)(hb + (size_t)d1 * NHD + lane * 4);
    v0 = v0 >= 0.f ? v0 : SLOPE * v0;
    v1 = v1 >= 0.f ? v1 : SLOPE * v1;
    float e0 = __expf(v0), e1 = __expf(v1);
    den += e0 + e1;
    acc.x += e0 * bf2f(h0.x) + e1 * bf2f(h1.x);
    acc.y += e0 * bf2f(h0.y) + e1 * bf2f(h1.y);
    acc.z += e0 * bf2f(h0.z) + e1 * bf2f(h1.z);
    acc.w += e0 * bf2f(h0.w) + e1 * bf2f(h1.w);
  }
  if (i < iend) {
    int d0 = edst[i];
    float v0 = ssrc + s_dst[d0 * 8 + head];
    v0 = v0 >= 0.f ? v0 : SLOPE * v0;
    float e0 = __expf(v0);
    u16x4 h0 = *(const u16x4*)(hb + (size_t)d0 * NHD + lane * 4);
    den += e0;
    acc.x += e0 * bf2f(h0.x);
    acc.y += e0 * bf2f(h0.y);
    acc.z += e0 * bf2f(h0.z);
    acc.w += e0 * bf2f(h0.w);
  }
  float inv = 1.f / (den + EPS_F);         // deg==0: acc=0 -> out=0
  *(f32x4*)(out + (size_t)n * NHD + lane * 4) = acc * inv;
}

extern "C" void kernel_launch(void* const* d_in, const int* in_sizes, int n_in,
                              void* d_out, int out_size, void* d_ws, size_t ws_size,
                              hipStream_t stream) {
  const float* x  = (const float*)d_in[0];
  const int*   ei = (const int*)d_in[1];
  const float* W  = (const float*)d_in[2];
  const float* a  = (const float*)d_in[3];
  float* out = (float*)d_out;

  // workspace layout (~33 MB, 16B-aligned blocks)
  unsigned short* hb  = (unsigned short*)d_ws;                 // 12,800,000 u16
  unsigned short* WbT = hb + (size_t)N_NODES * NHD;            // 131,072 u16
  float* s_src = (float*)(WbT + (size_t)NHD * IN_F);           // 400,000 f
  float* s_dst = s_src + (size_t)N_NODES * HEADS;              // 400,000 f
  int* deg    = (int*)(s_dst + (size_t)N_NODES * HEADS);       // 50,000
  int* cursor = deg + N_NODES;                                 // 50,000
  int* rowptr = cursor + N_NODES;                              // 50,001 (pad 50,008)
  int* bsum   = rowptr + 50008;                                // 196 (pad 256)
  int* edst   = bsum + 256;                                    // 800,000

  k_cast_w<<<512, 256, 0, stream>>>(W, WbT, deg);
  k_gemm_mfma<<<NB_GEMM + NB_HIST, 512, 0, stream>>>(x, WbT, hb, a, s_src, s_dst, ei, deg);
  k_bsum<<<N_SBLK, 256, 0, stream>>>(deg, bsum);
  k_scan_main<<<N_SBLK, 256, 0, stream>>>(deg, bsum, rowptr, cursor);
  k_fill<<<(N_EDGES + 255) / 256, 256, 0, stream>>>(ei, cursor, edst);
  k_aggr<<<(N_NODES * 64 + 255) / 256, 256, 0, stream>>>(rowptr, edst, s_src, s_dst, hb, out);
}